// Round 2
// baseline (39.705 us; speedup 1.0000x reference)
//
#include <hip/hip_runtime.h>
#include <math.h>

// Loss: per row i of output/target (B x 3 f32, uniform [0,1)):
//   ang = 2*pi*(x - 0.5); v = euler_to_vec(ang) for both; cross/dot;
//   per_sample = 1 - |cross| + dot; result = sum over B.
//
// HW note: v_sin_f32 / v_cos_f32 take input in REVOLUTIONS (D = sin(2*pi*S0)),
// so sin(2*pi*(x-0.5)) == __builtin_amdgcn_sinf(x - 0.5f). Input |x|<=0.5 is
// well inside the valid hardware domain; no range reduction needed.

#define NBLOCKS 2048
#define NTHREADS 256

__device__ __forceinline__ float sample_loss(float a, float b, float c,
                                             float d, float e, float f) {
  // output angles (revolutions)
  float oy = a - 0.5f, op = b - 0.5f, orr = c - 0.5f;
  float ty = d - 0.5f, tp = e - 0.5f, trr = f - 0.5f;

  float cy = __builtin_amdgcn_cosf(oy), sy = __builtin_amdgcn_sinf(oy);
  float cp = __builtin_amdgcn_cosf(op), sp = __builtin_amdgcn_sinf(op);
  float cr = __builtin_amdgcn_cosf(orr), sr = __builtin_amdgcn_sinf(orr);

  float vox = cy * sp * cr + sy * sr;
  float voy = sy * sp * cr - cy * sr;
  float voz = cp * cr;

  float cy2 = __builtin_amdgcn_cosf(ty), sy2 = __builtin_amdgcn_sinf(ty);
  float cp2 = __builtin_amdgcn_cosf(tp), sp2 = __builtin_amdgcn_sinf(tp);
  float cr2 = __builtin_amdgcn_cosf(trr), sr2 = __builtin_amdgcn_sinf(trr);

  float vtx = cy2 * sp2 * cr2 + sy2 * sr2;
  float vty = sy2 * sp2 * cr2 - cy2 * sr2;
  float vtz = cp2 * cr2;

  float crx = voy * vtz - voz * vty;
  float cry = voz * vtx - vox * vtz;
  float crz = vox * vty - voy * vtx;

  float cn = sqrtf(crx * crx + cry * cry + crz * crz);
  float dot = vox * vtx + voy * vty + voz * vtz;
  return 1.0f - cn + dot;
}

__device__ __forceinline__ float block_reduce(float acc) {
  // wave (64-lane) shuffle reduce, then LDS across the 4 waves
  #pragma unroll
  for (int off = 32; off > 0; off >>= 1) acc += __shfl_down(acc, off, 64);
  __shared__ float ws[NTHREADS / 64];
  int lane = threadIdx.x & 63;
  int wave = threadIdx.x >> 6;
  if (lane == 0) ws[wave] = acc;
  __syncthreads();
  float tot = 0.0f;
  if (threadIdx.x == 0) {
    #pragma unroll
    for (int w = 0; w < NTHREADS / 64; ++w) tot += ws[w];
  }
  return tot;  // valid in thread 0 only
}

__global__ __launch_bounds__(NTHREADS) void loss_partial_kernel(
    const float* __restrict__ out, const float* __restrict__ tgt,
    float* __restrict__ partial, int B) {
  const int tid = blockIdx.x * blockDim.x + threadIdx.x;
  const int nthreads = gridDim.x * blockDim.x;
  const int ngroups = B >> 2;  // groups of 4 rows = 12 floats = 3 float4

  const float4* __restrict__ o4 = (const float4*)out;
  const float4* __restrict__ t4 = (const float4*)tgt;

  float acc = 0.0f;
  for (int g = tid; g < ngroups; g += nthreads) {
    float4 o0 = o4[3 * g + 0];
    float4 o1 = o4[3 * g + 1];
    float4 o2 = o4[3 * g + 2];
    float4 t0 = t4[3 * g + 0];
    float4 t1 = t4[3 * g + 1];
    float4 t2 = t4[3 * g + 2];
    acc += sample_loss(o0.x, o0.y, o0.z, t0.x, t0.y, t0.z);
    acc += sample_loss(o0.w, o1.x, o1.y, t0.w, t1.x, t1.y);
    acc += sample_loss(o1.z, o1.w, o2.x, t1.z, t1.w, t2.x);
    acc += sample_loss(o2.y, o2.z, o2.w, t2.y, t2.z, t2.w);
  }
  // tail rows (B not divisible by 4) — scalar, distributed
  for (int r = (ngroups << 2) + tid; r < B; r += nthreads) {
    acc += sample_loss(out[3 * r], out[3 * r + 1], out[3 * r + 2],
                       tgt[3 * r], tgt[3 * r + 1], tgt[3 * r + 2]);
  }

  float tot = block_reduce(acc);
  if (threadIdx.x == 0) partial[blockIdx.x] = tot;
}

__global__ __launch_bounds__(NTHREADS) void final_reduce_kernel(
    const float* __restrict__ partial, int n, float* __restrict__ out) {
  float acc = 0.0f;
  for (int i = threadIdx.x; i < n; i += NTHREADS) acc += partial[i];
  float tot = block_reduce(acc);
  if (threadIdx.x == 0) out[0] = tot;
}

extern "C" void kernel_launch(void* const* d_in, const int* in_sizes, int n_in,
                              void* d_out, int out_size, void* d_ws, size_t ws_size,
                              hipStream_t stream) {
  const float* d_output = (const float*)d_in[0];
  const float* d_target = (const float*)d_in[1];
  float* partial = (float*)d_ws;      // NBLOCKS floats of scratch
  float* out = (float*)d_out;         // 1 float
  const int B = in_sizes[0] / 3;

  loss_partial_kernel<<<NBLOCKS, NTHREADS, 0, stream>>>(d_output, d_target,
                                                        partial, B);
  final_reduce_kernel<<<1, NTHREADS, 0, stream>>>(partial, NBLOCKS, out);
}

// Round 3
// 37.999 us; speedup vs baseline: 1.0449x; 1.0449x over previous
//
#include <hip/hip_runtime.h>
#include <math.h>

// Loss: per row i of output/target (B x 3 f32):
//   ang = 2*pi*(x-0.5); v = euler_to_vec(ang); per = 1 - |cross(vo,vt)| + dot(vo,vt)
//   result = sum over B.
//
// R2 design notes:
// - v_sin/v_cos take REVOLUTIONS: sin(2*pi*(x-0.5)) == __builtin_amdgcn_sinf(x-0.5f).
// - 12-byte AoS rows make direct float4 loads 48B-lane-strided -> 3x cache-line
//   probe amplification (measured ~5.1 TB/s ceiling in R1). Fix: dense float2
//   staging into LDS, then per-row LDS reads (3t%32 banks -> 2-way = free).
// - T14 pipeline: issue next tile's global loads between the barriers so L3
//   latency hides under this tile's compute.

#define NBLOCKS 1024
#define NTHREADS 512
#define TILE_ROWS 1024                 // rows per block-iteration
#define TILE_F2 (TILE_ROWS * 3 / 2)    // 1536 float2 per input = 12 KB

__device__ __forceinline__ float sample_loss(float a, float b, float c,
                                             float d, float e, float f) {
  float oy = a - 0.5f, op = b - 0.5f, orr = c - 0.5f;
  float ty = d - 0.5f, tp = e - 0.5f, trr = f - 0.5f;

  float cy = __builtin_amdgcn_cosf(oy), sy = __builtin_amdgcn_sinf(oy);
  float cp = __builtin_amdgcn_cosf(op), sp = __builtin_amdgcn_sinf(op);
  float cr = __builtin_amdgcn_cosf(orr), sr = __builtin_amdgcn_sinf(orr);

  float vox = cy * sp * cr + sy * sr;
  float voy = sy * sp * cr - cy * sr;
  float voz = cp * cr;

  float cy2 = __builtin_amdgcn_cosf(ty), sy2 = __builtin_amdgcn_sinf(ty);
  float cp2 = __builtin_amdgcn_cosf(tp), sp2 = __builtin_amdgcn_sinf(tp);
  float cr2 = __builtin_amdgcn_cosf(trr), sr2 = __builtin_amdgcn_sinf(trr);

  float vtx = cy2 * sp2 * cr2 + sy2 * sr2;
  float vty = sy2 * sp2 * cr2 - cy2 * sr2;
  float vtz = cp2 * cr2;

  float crx = voy * vtz - voz * vty;
  float cry = voz * vtx - vox * vtz;
  float crz = vox * vty - voy * vtx;

  float cn = sqrtf(crx * crx + cry * cry + crz * crz);
  float dot = vox * vtx + voy * vty + voz * vtz;
  return 1.0f - cn + dot;
}

template <int NT>
__device__ __forceinline__ float block_reduce(float acc) {
  #pragma unroll
  for (int off = 32; off > 0; off >>= 1) acc += __shfl_down(acc, off, 64);
  __shared__ float ws[NT / 64];
  int lane = threadIdx.x & 63;
  int wave = threadIdx.x >> 6;
  if (lane == 0) ws[wave] = acc;
  __syncthreads();
  float tot = 0.0f;
  if (threadIdx.x == 0) {
    #pragma unroll
    for (int w = 0; w < NT / 64; ++w) tot += ws[w];
  }
  return tot;  // valid in thread 0 only
}

__global__ __launch_bounds__(NTHREADS) void loss_partial_kernel(
    const float* __restrict__ out, const float* __restrict__ tgt,
    float* __restrict__ partial, int B) {
  __shared__ float2 ldsO2[TILE_F2];
  __shared__ float2 ldsT2[TILE_F2];
  const float* ldsO = (const float*)ldsO2;
  const float* ldsT = (const float*)ldsT2;

  const float2* __restrict__ o2 = (const float2*)out;
  const float2* __restrict__ t2 = (const float2*)tgt;

  const int t = threadIdx.x;
  const int ntiles = B / TILE_ROWS;

  float acc = 0.0f;

  int tile = blockIdx.x;
  float2 a0, a1, a2, b0, b1, b2;
  if (tile < ntiles) {
    const int g = tile * TILE_F2 + t;
    a0 = o2[g]; a1 = o2[g + NTHREADS]; a2 = o2[g + 2 * NTHREADS];
    b0 = t2[g]; b1 = t2[g + NTHREADS]; b2 = t2[g + 2 * NTHREADS];
  }

  while (tile < ntiles) {
    // write staged tile to LDS (dense float2, standard conflict-free pattern)
    ldsO2[t] = a0; ldsO2[t + NTHREADS] = a1; ldsO2[t + 2 * NTHREADS] = a2;
    ldsT2[t] = b0; ldsT2[t + NTHREADS] = b1; ldsT2[t + 2 * NTHREADS] = b2;
    __syncthreads();

    // T14: issue NEXT tile's global loads now; latency hides under compute.
    const int next = tile + gridDim.x;
    if (next < ntiles) {
      const int g = next * TILE_F2 + t;
      a0 = o2[g]; a1 = o2[g + NTHREADS]; a2 = o2[g + 2 * NTHREADS];
      b0 = t2[g]; b1 = t2[g + NTHREADS]; b2 = t2[g + 2 * NTHREADS];
    }

    // compute this tile from LDS: rows t + k*NTHREADS
    #pragma unroll
    for (int k = 0; k < TILE_ROWS / NTHREADS; ++k) {
      const int r = t + k * NTHREADS;
      acc += sample_loss(ldsO[3 * r], ldsO[3 * r + 1], ldsO[3 * r + 2],
                         ldsT[3 * r], ldsT[3 * r + 1], ldsT[3 * r + 2]);
    }
    __syncthreads();  // reads done before next iteration overwrites LDS
    tile = next;
  }

  // tail rows (B not divisible by TILE_ROWS) — scalar, distributed
  const int done = ntiles * TILE_ROWS;
  for (int r = done + blockIdx.x * NTHREADS + t; r < B;
       r += gridDim.x * NTHREADS) {
    acc += sample_loss(out[3 * r], out[3 * r + 1], out[3 * r + 2],
                       tgt[3 * r], tgt[3 * r + 1], tgt[3 * r + 2]);
  }

  float tot = block_reduce<NTHREADS>(acc);
  if (t == 0) partial[blockIdx.x] = tot;
}

__global__ __launch_bounds__(256) void final_reduce_kernel(
    const float* __restrict__ partial, int n, float* __restrict__ out) {
  float acc = 0.0f;
  for (int i = threadIdx.x; i < n; i += 256) acc += partial[i];
  float tot = block_reduce<256>(acc);
  if (threadIdx.x == 0) out[0] = tot;
}

extern "C" void kernel_launch(void* const* d_in, const int* in_sizes, int n_in,
                              void* d_out, int out_size, void* d_ws, size_t ws_size,
                              hipStream_t stream) {
  const float* d_output = (const float*)d_in[0];
  const float* d_target = (const float*)d_in[1];
  float* partial = (float*)d_ws;  // NBLOCKS floats of scratch
  float* out = (float*)d_out;     // 1 float
  const int B = in_sizes[0] / 3;

  loss_partial_kernel<<<NBLOCKS, NTHREADS, 0, stream>>>(d_output, d_target,
                                                        partial, B);
  final_reduce_kernel<<<1, 256, 0, stream>>>(partial, NBLOCKS, out);
}